// Round 1
// baseline (1107.620 us; speedup 1.0000x reference)
//
#include <hip/hip_runtime.h>

#define LQ 256
#define EDGES 65536
#define NNODE 1024
#define ET 32
#define NCHUNK 13

constexpr float PW0c = 0.15811388300841897f;   // sqrt(1/40)
constexpr float PW1c = 0.25f;
constexpr float S3c  = 0.57735026918962576f;   // 1/sqrt(3)
constexpr float Kc   = 0.54772255750516611f;   // sqrt(3/10)

__device__ __forceinline__ float red8(float v){
  v += __shfl_xor(v, 1);
  v += __shfl_xor(v, 2);
  v += __shfl_xor(v, 4);
  return v;
}

// ---- feats = [node @ proj_l0_w + b | l1_feats], padded to stride 64
__global__ __launch_bounds__(64) void feats_kernel(
    const float* __restrict__ node, const float* __restrict__ l1,
    const float* __restrict__ w, const float* __restrict__ b,
    float* __restrict__ feats)
{
  const int rr = blockIdx.x;
  const int t = threadIdx.x;
  if (t < 32){
    float acc = b[t];
    const float* nr = node + rr*256;
    #pragma unroll 4
    for (int c=0;c<256;c++) acc += nr[c]*w[c*32+t];
    feats[rr*64+t] = acc;
  } else if (t < 56){
    feats[rr*64+t] = l1[rr*24 + (t-32)];
  }
}

__global__ __launch_bounds__(256) void count_kernel(
    const int* __restrict__ src, float* __restrict__ cnt)
{
  const int ee = blockIdx.x*256 + threadIdx.x;
  atomicAdd(&cnt[src[ee]], 1.0f);
}

// ---- fused LN -> fc1 -> fc2 -> tensor product -> segment atomic add
__global__ __launch_bounds__(256) void edge_kernel(
    const float* __restrict__ pair, const int* __restrict__ pidx,
    const int* __restrict__ esrc, const int* __restrict__ edst,
    const float* __restrict__ esh,
    const float* __restrict__ lng, const float* __restrict__ lnb,
    const float* __restrict__ fc1w, const float* __restrict__ fc1b,
    const float* __restrict__ fc2w, const float* __restrict__ fc2b,
    const float* __restrict__ feats, float* __restrict__ sums)
{
  __shared__ float sBuf[4608];        // xn [32][128], later wch_t [128][36]
  __shared__ float sH[4608];          // h_t [128][36] : sH[j*36 + e]
  __shared__ float sC[ET*129];        // per-edge TP coefficients, pad 129
  __shared__ int s_src[ET], s_dst[ET];

  const int t = threadIdx.x;
  const int e0g = blockIdx.x * ET;

  if (t < ET){ s_src[t] = esrc[e0g+t]; s_dst[t] = edst[e0g+t]; }
  __syncthreads();

  const int e = t >> 3;   // 0..31 edge in tile
  const int r = t & 7;    // 0..7 sub-thread

  // ---- phase 0: tensor-product coefficient vectors (needs feats[dst], sh)
  {
    const float* f = feats + (size_t)s_dst[e]*64;
    const float* sh = esh + (size_t)(e0g+e)*9;
    const float sh0 = sh[0], s1x = sh[1], s1y = sh[2], s1z = sh[3];
    float* C = sC + e*129;
    #pragma unroll
    for (int q=0;q<4;q++){
      const int u = r*4+q;
      const float x0u = f[u];
      C[u]    = PW0c*sh0*x0u;          // c1[u]
      C[40+u] = PW1c*S3c*x0u;          // cx0[u]
    }
    {
      const int u = r;
      const float xx = f[32+u*3+0], xy = f[32+u*3+1], xz = f[32+u*3+2];
      C[32+u] = PW0c*S3c*(xx*s1x + xy*s1y + xz*s1z);   // c4[u]
      const float bc = PW1c*S3c*sh0;
      C[72+u*3+0] = bc*xx; C[72+u*3+1] = bc*xy; C[72+u*3+2] = bc*xz;  // b3[u][m]
      const float s20=sh[4], s21=sh[5], s22=sh[6], s23=sh[7], s24=sh[8];
      const float RXX = Kc*(-(1.f/3.f)*s22 - S3c*s24);
      const float RXY = Kc*S3c*s21;
      const float RXZ = Kc*S3c*s20;
      const float RYX = Kc*S3c*s21;
      const float RYY = Kc*((2.f/3.f)*s22);
      const float RYZ = Kc*S3c*s23;
      const float RZX = Kc*S3c*s20;
      const float RZY = Kc*S3c*s23;
      const float RZZ = Kc*(-(1.f/3.f)*s22 + S3c*s24);
      C[96+u*3+0] = PW1c*(xx*RXX + xy*RYX + xz*RZX);   // t5p[u][m]
      C[96+u*3+1] = PW1c*(xx*RXY + xy*RYY + xz*RZY);
      C[96+u*3+2] = PW1c*(xx*RXZ + xy*RYZ + xz*RZZ);
      if (r==0){ C[120]=s1x; C[121]=s1y; C[122]=s1z; }
    }
  }

  // ---- phase 1: gather pair row + LayerNorm -> sBuf[e][c]
  {
    const int ee = e0g + e;
    const int pb = pidx[ee], pi_ = pidx[EDGES+ee], pj = pidx[2*EDGES+ee];
    const float4* prow = (const float4*)(pair + (((size_t)pb*LQ + pi_)*LQ + pj)*128);
    float4 v[4];
    #pragma unroll
    for (int k=0;k<4;k++) v[k] = prow[r*4+k];
    float s=0.f, s2=0.f;
    #pragma unroll
    for (int k=0;k<4;k++){
      s  += v[k].x+v[k].y+v[k].z+v[k].w;
      s2 += v[k].x*v[k].x + v[k].y*v[k].y + v[k].z*v[k].z + v[k].w*v[k].w;
    }
    s = red8(s); s2 = red8(s2);
    const float mean = s * (1.f/128.f);
    const float var  = s2 * (1.f/128.f) - mean*mean;
    const float rstd = rsqrtf(var + 1e-5f);
    #pragma unroll
    for (int k=0;k<4;k++){
      const int c = r*16 + k*4;
      const float4 g  = *(const float4*)(lng + c);
      const float4 bb = *(const float4*)(lnb + c);
      float4 o;
      o.x = (v[k].x-mean)*rstd*g.x + bb.x;
      o.y = (v[k].y-mean)*rstd*g.y + bb.y;
      o.z = (v[k].z-mean)*rstd*g.z + bb.z;
      o.w = (v[k].w-mean)*rstd*g.w + bb.w;
      *(float4*)&sBuf[e*128 + c] = o;
    }
  }
  __syncthreads();

  // ---- phase 2: h = relu(xn @ fc1w + fc1b) -> sH[j*36 + e] (transposed)
  {
    const float* xn = sBuf + e*128;
    #pragma unroll
    for (int p=0;p<4;p++){
      const int j0 = p*32 + r*4;
      float a0=fc1b[j0+0], a1=fc1b[j0+1], a2=fc1b[j0+2], a3=fc1b[j0+3];
      #pragma unroll 4
      for (int c=0;c<128;c++){
        const float xv = xn[c];
        const float4 wv = *(const float4*)(fc1w + c*128 + j0);
        a0 += xv*wv.x; a1 += xv*wv.y; a2 += xv*wv.z; a3 += xv*wv.w;
      }
      sH[(j0+0)*36+e] = fmaxf(a0,0.f);
      sH[(j0+1)*36+e] = fmaxf(a1,0.f);
      sH[(j0+2)*36+e] = fmaxf(a2,0.f);
      sH[(j0+3)*36+e] = fmaxf(a3,0.f);
    }
  }
  __syncthreads();

  // ---- phase 3: 13 chunks of 128 j: w-chunk GEMM then TP scatter-apply
  const int eg  = t >> 5;       // 0..7  (w-compute e-group)
  const int jgw = t & 31;       // 0..31 (w-compute j-group)
  const int ew0 = eg*4;
  const int ea  = e;            // apply-side edge
  const int wi0 = r*4;          // out0 ownership: wi0..wi0+3
  const int wi1 = r;            // out1 ownership: row wi1, m=0..2
  const float* Ca = sC + ea*129;

  float o0[4] = {0.f,0.f,0.f,0.f};
  float o1[3] = {0.f,0.f,0.f};

  for (int cb=0; cb<NCHUNK; cb++){
    float4 acc[4];
    {
      const int j0 = cb*128 + jgw*4;
      const float4 bv = *(const float4*)(fc2b + j0);
      acc[0] = make_float4(bv.x,bv.x,bv.x,bv.x);
      acc[1] = make_float4(bv.y,bv.y,bv.y,bv.y);
      acc[2] = make_float4(bv.z,bv.z,bv.z,bv.z);
      acc[3] = make_float4(bv.w,bv.w,bv.w,bv.w);
      const float* wp = fc2w + j0;
      #pragma unroll 2
      for (int c=0;c<128;c++){
        const float4 hv = *(const float4*)(sH + c*36 + ew0);
        const float4 wv = *(const float4*)(wp + (size_t)c*1664);
        acc[0].x += wv.x*hv.x; acc[0].y += wv.x*hv.y; acc[0].z += wv.x*hv.z; acc[0].w += wv.x*hv.w;
        acc[1].x += wv.y*hv.x; acc[1].y += wv.y*hv.y; acc[1].z += wv.y*hv.z; acc[1].w += wv.y*hv.w;
        acc[2].x += wv.z*hv.x; acc[2].y += wv.z*hv.y; acc[2].z += wv.z*hv.z; acc[2].w += wv.z*hv.w;
        acc[3].x += wv.w*hv.x; acc[3].y += wv.w*hv.y; acc[3].z += wv.w*hv.z; acc[3].w += wv.w*hv.w;
      }
    }
    __syncthreads();   // previous apply (or phase2 reads) done with sBuf
    #pragma unroll
    for (int ji=0;ji<4;ji++)
      *(float4*)&sBuf[(jgw*4+ji)*36 + ew0] = acc[ji];   // wch_t[jj][e]
    __syncthreads();   // wch visible

    if (cb < 8){                       // W1: u0 = cb*4
      const int u0 = cb*4;
      #pragma unroll
      for (int q=0;q<4;q++){
        const int wi = wi0+q;
        float sacc = 0.f;
        #pragma unroll
        for (int du=0;du<4;du++)
          sacc += Ca[u0+du]*sBuf[(du*32+wi)*36+ea];
        o0[q] += sacc;
      }
    } else if (cb < 10){               // W2: u0 = (cb-8)*16
      const int u0 = (cb-8)*16;
      float S = 0.f;
      #pragma unroll
      for (int du=0;du<16;du++)
        S += Ca[40+u0+du]*sBuf[(du*8+wi1)*36+ea];
      o1[0] += S*Ca[120]; o1[1] += S*Ca[121]; o1[2] += S*Ca[122];
    } else if (cb == 10){              // W3 (jj<64) + W4 u=0,1 (jj>=64)
      #pragma unroll
      for (int u=0;u<8;u++){
        const float wv = sBuf[(u*8+wi1)*36+ea];
        o1[0] += Ca[72+u*3+0]*wv;
        o1[1] += Ca[72+u*3+1]*wv;
        o1[2] += Ca[72+u*3+2]*wv;
      }
      #pragma unroll
      for (int q=0;q<4;q++){
        const int wi = wi0+q;
        o0[q] += Ca[32+0]*sBuf[(64+wi)*36+ea] + Ca[32+1]*sBuf[(96+wi)*36+ea];
      }
    } else if (cb == 11){              // W4 u=2..5
      #pragma unroll
      for (int q=0;q<4;q++){
        const int wi = wi0+q;
        #pragma unroll
        for (int du=0;du<4;du++)
          o0[q] += Ca[32+2+du]*sBuf[(du*32+wi)*36+ea];
      }
    } else {                           // cb==12: W4 u=6,7 (jj<64) + W5 (jj>=64)
      #pragma unroll
      for (int q=0;q<4;q++){
        const int wi = wi0+q;
        o0[q] += Ca[32+6]*sBuf[(wi)*36+ea] + Ca[32+7]*sBuf[(32+wi)*36+ea];
      }
      #pragma unroll
      for (int u=0;u<8;u++){
        const float wv = sBuf[(64+u*8+wi1)*36+ea];
        o1[0] += Ca[96+u*3+0]*wv;
        o1[1] += Ca[96+u*3+1]*wv;
        o1[2] += Ca[96+u*3+2]*wv;
      }
    }
  }

  float* srow = sums + (size_t)s_src[ea]*64;
  #pragma unroll
  for (int q=0;q<4;q++) atomicAdd(srow + wi0 + q, o0[q]);
  #pragma unroll
  for (int m=0;m<3;m++) atomicAdd(srow + 32 + wi1*3 + m, o1[m]);
}

// ---- finalize: mean, node projection + residuals, write outputs
__global__ __launch_bounds__(256) void finalize_kernel(
    const float* __restrict__ sums, const float* __restrict__ cnt,
    const float* __restrict__ node, const float* __restrict__ l1,
    const float* __restrict__ pw, const float* __restrict__ pb,
    float* __restrict__ out)
{
  __shared__ float so[56];
  const int rnode = blockIdx.x;
  const int t = threadIdx.x;
  if (t < 56){
    const float c = cnt[rnode];
    so[t] = sums[rnode*64+t] / fmaxf(c, 1.0f);
  }
  __syncthreads();
  float acc = pb[t] + node[rnode*256+t];
  #pragma unroll
  for (int k=0;k<32;k++) acc += so[k]*pw[k*256+t];
  out[rnode*256+t] = acc;
  if (t < 24) out[NNODE*256 + rnode*24 + t] = so[32+t] + l1[rnode*24+t];
}

extern "C" void kernel_launch(void* const* d_in, const int* in_sizes, int n_in,
                              void* d_out, int out_size, void* d_ws, size_t ws_size,
                              hipStream_t stream)
{
  const float* node = (const float*)d_in[0];
  const float* pair = (const float*)d_in[1];
  const float* l1f  = (const float*)d_in[2];
  const float* esh  = (const float*)d_in[3];
  const float* plw  = (const float*)d_in[4];
  const float* plb  = (const float*)d_in[5];
  const float* pnw  = (const float*)d_in[6];
  const float* pnb  = (const float*)d_in[7];
  const float* lng  = (const float*)d_in[8];
  const float* lnb  = (const float*)d_in[9];
  const float* fc1w = (const float*)d_in[10];
  const float* fc1b = (const float*)d_in[11];
  const float* fc2w = (const float*)d_in[12];
  const float* fc2b = (const float*)d_in[13];
  const int* pidx = (const int*)d_in[14];
  const int* esrc = (const int*)d_in[15];
  const int* edst = (const int*)d_in[16];
  float* out = (float*)d_out;
  float* ws = (float*)d_ws;
  float* feats = ws;             // 1024*64
  float* sums  = ws + 65536;     // 1024*64
  float* cnt   = ws + 131072;    // 1024

  hipMemsetAsync(sums, 0, (65536+1024)*sizeof(float), stream);
  feats_kernel<<<dim3(1024), dim3(64), 0, stream>>>(node, l1f, plw, plb, feats);
  count_kernel<<<dim3(256), dim3(256), 0, stream>>>(esrc, cnt);
  edge_kernel<<<dim3(2048), dim3(256), 0, stream>>>(pair, pidx, esrc, edst, esh,
      lng, lnb, fc1w, fc1b, fc2w, fc2b, feats, sums);
  finalize_kernel<<<dim3(1024), dim3(256), 0, stream>>>(sums, cnt, node, l1f, pnw, pnb, out);
}

// Round 2
// 442.046 us; speedup vs baseline: 2.5057x; 2.5057x over previous
//
#include <hip/hip_runtime.h>

#define LQ 256
#define EDGES 65536
#define NNODE 1024
#define ET 64
#define NT 512
#define WSTR 66

typedef __attribute__((ext_vector_type(8))) short bf16x8;
typedef __attribute__((ext_vector_type(4))) float f32x4;
typedef unsigned short ushort_t;
typedef unsigned int uint32;

constexpr float PW0c = 0.15811388300841897f;   // sqrt(1/40)
constexpr float PW1c = 0.25f;
constexpr float S3c  = 0.57735026918962576f;   // 1/sqrt(3)
constexpr float Kc   = 0.54772255750516611f;   // sqrt(3/10)

__device__ __forceinline__ ushort_t f2bf(float x){
  unsigned u = __float_as_uint(x);
  unsigned r = u + 0x7FFFu + ((u >> 16) & 1u);
  return (ushort_t)(r >> 16);
}

__device__ __forceinline__ float red8(float v){
  v += __shfl_xor(v, 1);
  v += __shfl_xor(v, 2);
  v += __shfl_xor(v, 4);
  return v;
}

// ---- pre-transpose + bf16-convert fc1w/fc2w: out[j][k] = in[k][j]
__global__ __launch_bounds__(512) void prep_kernel(
    const float* __restrict__ fc1w, const float* __restrict__ fc2w,
    ushort_t* __restrict__ fc1wT, ushort_t* __restrict__ fc2wT)
{
  const int i = blockIdx.x*512 + threadIdx.x;
  if (i < 16384){
    const int j = i >> 7, k = i & 127;
    fc1wT[i] = f2bf(fc1w[k*128 + j]);
  } else {
    const int i2 = i - 16384;
    const int j = i2 >> 7, k = i2 & 127;
    fc2wT[i2] = f2bf(fc2w[(size_t)k*1664 + j]);
  }
}

// ---- feats = [node @ proj_l0_w + b | l1_feats], padded to stride 64
__global__ __launch_bounds__(64) void feats_kernel(
    const float* __restrict__ node, const float* __restrict__ l1,
    const float* __restrict__ w, const float* __restrict__ b,
    float* __restrict__ feats)
{
  const int rr = blockIdx.x;
  const int t = threadIdx.x;
  if (t < 32){
    float acc = b[t];
    const float* nr = node + rr*256;
    #pragma unroll 4
    for (int c=0;c<256;c++) acc += nr[c]*w[c*32+t];
    feats[rr*64+t] = acc;
  } else if (t < 56){
    feats[rr*64+t] = l1[rr*24 + (t-32)];
  }
}

__global__ __launch_bounds__(256) void count_kernel(
    const int* __restrict__ src, float* __restrict__ cnt)
{
  const int ee = blockIdx.x*256 + threadIdx.x;
  atomicAdd(&cnt[src[ee]], 1.0f);
}

// ================= fused MFMA edge kernel =================
__global__ __launch_bounds__(NT) void edge_kernel(
    const float* __restrict__ pair, const int* __restrict__ pidx,
    const int* __restrict__ esrc, const int* __restrict__ edst,
    const float* __restrict__ esh,
    const float* __restrict__ lng, const float* __restrict__ lnb,
    const ushort_t* __restrict__ fc1wT, const float* __restrict__ fc1b,
    const ushort_t* __restrict__ fc2wT, const float* __restrict__ fc2b,
    const float* __restrict__ feats, float* __restrict__ sums)
{
  __shared__ float sWch[128*WSTR];          // w-chunk f32 [j][66] ; overlaid: xn bf16 [64][128] swizzled
  __shared__ unsigned char sH[64*256];      // h bf16 [e][128] swizzled
  __shared__ unsigned char sBt[128*256];    // B^T bf16 [j][128k] swizzled
  __shared__ float sC[ET*129];              // per-edge TP coefficients
  __shared__ int s_src[ET], s_dst[ET];

  const int t = threadIdx.x;
  const int e0g = blockIdx.x * ET;
  unsigned char* xnb = (unsigned char*)sWch;

  if (t < ET){ s_src[t] = esrc[e0g+t]; s_dst[t] = edst[e0g+t]; }

  const uint4* gW1 = (const uint4*)fc1wT;
  const uint4* gW2 = (const uint4*)fc2wT;
  uint4 pfA[4], pfB[4];
  #pragma unroll
  for (int u=0;u<4;u++) pfA[u] = gW1[u*NT + t];   // fc1wT in flight

  __syncthreads();

  const int e = t >> 3;   // 0..63 edge in tile
  const int r = t & 7;    // 0..7 sub-thread

  // ---- phase 0: tensor-product coefficient vectors
  {
    const float* f = feats + (size_t)s_dst[e]*64;
    const float* sh = esh + (size_t)(e0g+e)*9;
    const float sh0 = sh[0], s1x = sh[1], s1y = sh[2], s1z = sh[3];
    float* C = sC + e*129;
    #pragma unroll
    for (int q=0;q<4;q++){
      const int u = r*4+q;
      const float x0u = f[u];
      C[u]    = PW0c*sh0*x0u;          // c1[u]
      C[40+u] = PW1c*S3c*x0u;          // cx0[u]
    }
    {
      const int u = r;
      const float xx = f[32+u*3+0], xy = f[32+u*3+1], xz = f[32+u*3+2];
      C[32+u] = PW0c*S3c*(xx*s1x + xy*s1y + xz*s1z);   // c4[u]
      const float bc = PW1c*S3c*sh0;
      C[72+u*3+0] = bc*xx; C[72+u*3+1] = bc*xy; C[72+u*3+2] = bc*xz;  // b3[u][m]
      const float s20=sh[4], s21=sh[5], s22=sh[6], s23=sh[7], s24=sh[8];
      const float RXX = Kc*(-(1.f/3.f)*s22 - S3c*s24);
      const float RXY = Kc*S3c*s21;
      const float RXZ = Kc*S3c*s20;
      const float RYY = Kc*((2.f/3.f)*s22);
      const float RYZ = Kc*S3c*s23;
      const float RZZ = Kc*(-(1.f/3.f)*s22 + S3c*s24);
      C[96+u*3+0] = PW1c*(xx*RXX + xy*RXY + xz*RXZ);
      C[96+u*3+1] = PW1c*(xx*RXY + xy*RYY + xz*RYZ);
      C[96+u*3+2] = PW1c*(xx*RXZ + xy*RYZ + xz*RZZ);
      if (r==0){ C[120]=s1x; C[121]=s1y; C[122]=s1z; }
    }
  }

  // ---- phase 1: gather pair row + LayerNorm -> xn (bf16, swizzled)
  {
    const int ee = e0g + e;
    const int pb = pidx[ee], pi_ = pidx[EDGES+ee], pj = pidx[2*EDGES+ee];
    const float4* prow = (const float4*)(pair + (((size_t)pb*LQ + pi_)*LQ + pj)*128);
    float4 v[4];
    #pragma unroll
    for (int k=0;k<4;k++) v[k] = prow[r*4+k];
    float s=0.f, s2=0.f;
    #pragma unroll
    for (int k=0;k<4;k++){
      s  += v[k].x+v[k].y+v[k].z+v[k].w;
      s2 += v[k].x*v[k].x + v[k].y*v[k].y + v[k].z*v[k].z + v[k].w*v[k].w;
    }
    s = red8(s); s2 = red8(s2);
    const float mean = s * (1.f/128.f);
    const float var  = s2 * (1.f/128.f) - mean*mean;
    const float rstd = rsqrtf(var + 1e-5f);
    uint32 pk[8];
    #pragma unroll
    for (int k=0;k<4;k++){
      const int c = r*16 + k*4;
      const float4 g  = *(const float4*)(lng + c);
      const float4 bb = *(const float4*)(lnb + c);
      float4 o;
      o.x = (v[k].x-mean)*rstd*g.x + bb.x;
      o.y = (v[k].y-mean)*rstd*g.y + bb.y;
      o.z = (v[k].z-mean)*rstd*g.z + bb.z;
      o.w = (v[k].w-mean)*rstd*g.w + bb.w;
      pk[k*2]   = (uint32)f2bf(o.x) | ((uint32)f2bf(o.y)<<16);
      pk[k*2+1] = (uint32)f2bf(o.z) | ((uint32)f2bf(o.w)<<16);
    }
    const int xr = (e&7)<<4;
    *(uint4*)(xnb + e*256 + ((r*32) ^ xr))      = make_uint4(pk[0],pk[1],pk[2],pk[3]);
    *(uint4*)(xnb + e*256 + ((r*32+16) ^ xr))   = make_uint4(pk[4],pk[5],pk[6],pk[7]);
  }

  // stage fc1wT -> sBt (swizzled)
  #pragma unroll
  for (int u=0;u<4;u++){
    const int v = u*NT + t; const int n = v>>4; const int c = v&15;
    *(uint4*)(sBt + n*256 + ((c*16) ^ ((n&7)<<4))) = pfA[u];
  }
  // issue chunk-0 loads
  #pragma unroll
  for (int u=0;u<4;u++) pfB[u] = gW2[u*NT + t];
  __syncthreads();

  // ---- wave/lane decode for MFMA
  const int l = t & 63;
  const int l15 = l & 15;
  const int lh = l >> 4;                 // 0..3
  const int wv = t >> 6;                 // wave 0..7
  const int mt0 = (wv & 1) * 2;          // edge-tile pair: rows (mt0..mt0+1)*16
  const int npr = wv >> 1;               // j-tile pair 0..3
  const int erow0 = mt0*16 + l15;
  const int ax = (l15 & 7) << 4;         // XOR for A rows (row&7 == l15&7)
  const int jc0 = npr*32 + l15;          // local j col (j and j+16)
  const int bx = ax;                     // (jc0&7)==l15&7
  const int ebase = mt0*16 + lh*4;

  // ---- fc1: h = relu(xn @ fc1w + b) via MFMA
  {
    const float bj0 = fc1b[jc0], bj1 = fc1b[jc0+16];
    f32x4 acc00 = {bj0,bj0,bj0,bj0}, acc01 = {bj1,bj1,bj1,bj1};
    f32x4 acc10 = acc00, acc11 = acc01;
    #pragma unroll
    for (int kk=0;kk<4;kk++){
      const int ko = kk*64 + lh*16;
      bf16x8 a0 = *(const bf16x8*)(xnb + erow0*256 + (ko ^ ax));
      bf16x8 a1 = *(const bf16x8*)(xnb + (erow0+16)*256 + (ko ^ ax));
      bf16x8 b0 = *(const bf16x8*)(sBt + jc0*256 + (ko ^ bx));
      bf16x8 b1 = *(const bf16x8*)(sBt + (jc0+16)*256 + (ko ^ bx));
      acc00 = __builtin_amdgcn_mfma_f32_16x16x32_bf16(a0,b0,acc00,0,0,0);
      acc01 = __builtin_amdgcn_mfma_f32_16x16x32_bf16(a0,b1,acc01,0,0,0);
      acc10 = __builtin_amdgcn_mfma_f32_16x16x32_bf16(a1,b0,acc10,0,0,0);
      acc11 = __builtin_amdgcn_mfma_f32_16x16x32_bf16(a1,b1,acc11,0,0,0);
    }
    #pragma unroll
    for (int q=0;q<4;q++){
      const int ea = ebase + q, eb = ea + 16;
      *(ushort_t*)(sH + ea*256 + ((jc0*2) ^ ((ea&7)<<4)))      = f2bf(fmaxf(acc00[q],0.f));
      *(ushort_t*)(sH + ea*256 + (((jc0+16)*2) ^ ((ea&7)<<4))) = f2bf(fmaxf(acc01[q],0.f));
      *(ushort_t*)(sH + eb*256 + ((jc0*2) ^ ((eb&7)<<4)))      = f2bf(fmaxf(acc10[q],0.f));
      *(ushort_t*)(sH + eb*256 + (((jc0+16)*2) ^ ((eb&7)<<4))) = f2bf(fmaxf(acc11[q],0.f));
    }
  }
  __syncthreads();

  float o0[4] = {0.f,0.f,0.f,0.f};
  float o1[3] = {0.f,0.f,0.f};
  const float* Ca = sC + e*129;

#define APPLY(CB) do {                                                        \
    if ((CB) < 8){                                                            \
      const int u0 = (CB)*4;                                                  \
      _Pragma("unroll")                                                       \
      for (int q=0;q<4;q++){                                                  \
        const int wi = r*4+q;                                                 \
        float sacc = 0.f;                                                     \
        _Pragma("unroll")                                                     \
        for (int du=0;du<4;du++)                                              \
          sacc += Ca[u0+du]*sWch[(du*32+wi)*WSTR+e];                          \
        o0[q] += sacc;                                                        \
      }                                                                       \
    } else if ((CB) < 10){                                                    \
      const int u0 = ((CB)-8)*16;                                             \
      float S = 0.f;                                                          \
      _Pragma("unroll")                                                       \
      for (int du=0;du<16;du++)                                               \
        S += Ca[40+u0+du]*sWch[(du*8+r)*WSTR+e];                              \
      o1[0] += S*Ca[120]; o1[1] += S*Ca[121]; o1[2] += S*Ca[122];             \
    } else if ((CB) == 10){                                                   \
      _Pragma("unroll")                                                       \
      for (int u=0;u<8;u++){                                                  \
        const float wvv = sWch[(u*8+r)*WSTR+e];                               \
        o1[0] += Ca[72+u*3+0]*wvv;                                            \
        o1[1] += Ca[72+u*3+1]*wvv;                                            \
        o1[2] += Ca[72+u*3+2]*wvv;                                            \
      }                                                                       \
      _Pragma("unroll")                                                       \
      for (int q=0;q<4;q++){                                                  \
        const int wi = r*4+q;                                                 \
        o0[q] += Ca[32]*sWch[(64+wi)*WSTR+e] + Ca[33]*sWch[(96+wi)*WSTR+e];   \
      }                                                                       \
    } else if ((CB) == 11){                                                   \
      _Pragma("unroll")                                                       \
      for (int q=0;q<4;q++){                                                  \
        const int wi = r*4+q;                                                 \
        _Pragma("unroll")                                                     \
        for (int du=0;du<4;du++)                                              \
          o0[q] += Ca[34+du]*sWch[(du*32+wi)*WSTR+e];                         \
      }                                                                       \
    } else {                                                                  \
      _Pragma("unroll")                                                       \
      for (int q=0;q<4;q++){                                                  \
        const int wi = r*4+q;                                                 \
        o0[q] += Ca[38]*sWch[wi*WSTR+e] + Ca[39]*sWch[(32+wi)*WSTR+e];        \
      }                                                                       \
      _Pragma("unroll")                                                       \
      for (int u=0;u<8;u++){                                                  \
        const float wvv = sWch[(64+u*8+r)*WSTR+e];                            \
        o1[0] += Ca[96+u*3+0]*wvv;                                            \
        o1[1] += Ca[96+u*3+1]*wvv;                                            \
        o1[2] += Ca[96+u*3+2]*wvv;                                            \
      }                                                                       \
    }                                                                         \
  } while(0)

#define CHUNK(CB, CUR, NXT, DOLOAD) do {                                      \
    _Pragma("unroll")                                                         \
    for (int u=0;u<4;u++){                                                    \
      const int v = u*NT + t; const int n = v>>4; const int c = v&15;         \
      *(uint4*)(sBt + n*256 + ((c*16) ^ ((n&7)<<4))) = CUR[u];                \
    }                                                                         \
    if (DOLOAD){                                                              \
      _Pragma("unroll")                                                       \
      for (int u=0;u<4;u++) NXT[u] = gW2[((CB)+1)*2048 + u*NT + t];           \
    }                                                                         \
    __syncthreads();                                                          \
    {                                                                         \
      const float bj0 = fc2b[(CB)*128 + jc0];                                 \
      const float bj1 = fc2b[(CB)*128 + jc0 + 16];                            \
      f32x4 acc00 = {bj0,bj0,bj0,bj0}, acc01 = {bj1,bj1,bj1,bj1};             \
      f32x4 acc10 = acc00, acc11 = acc01;                                     \
      _Pragma("unroll")                                                       \
      for (int kk=0;kk<4;kk++){                                               \
        const int ko = kk*64 + lh*16;                                         \
        bf16x8 a0 = *(const bf16x8*)(sH + erow0*256 + (ko ^ ax));             \
        bf16x8 a1 = *(const bf16x8*)(sH + (erow0+16)*256 + (ko ^ ax));        \
        bf16x8 b0 = *(const bf16x8*)(sBt + jc0*256 + (ko ^ bx));              \
        bf16x8 b1 = *(const bf16x8*)(sBt + (jc0+16)*256 + (ko ^ bx));         \
        acc00 = __builtin_amdgcn_mfma_f32_16x16x32_bf16(a0,b0,acc00,0,0,0);   \
        acc01 = __builtin_amdgcn_mfma_f32_16x16x32_bf16(a0,b1,acc01,0,0,0);   \
        acc10 = __builtin_amdgcn_mfma_f32_16x16x32_bf16(a1,b0,acc10,0,0,0);   \
        acc11 = __builtin_amdgcn_mfma_f32_16x16x32_bf16(a1,b1,acc11,0,0,0);   \
      }                                                                       \
      _Pragma("unroll")                                                       \
      for (int q=0;q<4;q++){                                                  \
        sWch[jc0*WSTR + ebase + q]           = acc00[q];                      \
        sWch[(jc0+16)*WSTR + ebase + q]      = acc01[q];                      \
        sWch[jc0*WSTR + ebase + 16 + q]      = acc10[q];                      \
        sWch[(jc0+16)*WSTR + ebase + 16 + q] = acc11[q];                      \
      }                                                                       \
    }                                                                         \
    __syncthreads();                                                          \
    APPLY(CB);                                                                \
    __syncthreads();                                                          \
  } while(0)

  CHUNK(0,  pfB, pfA, 1);
  CHUNK(1,  pfA, pfB, 1);
  CHUNK(2,  pfB, pfA, 1);
  CHUNK(3,  pfA, pfB, 1);
  CHUNK(4,  pfB, pfA, 1);
  CHUNK(5,  pfA, pfB, 1);
  CHUNK(6,  pfB, pfA, 1);
  CHUNK(7,  pfA, pfB, 1);
  CHUNK(8,  pfB, pfA, 1);
  CHUNK(9,  pfA, pfB, 1);
  CHUNK(10, pfB, pfA, 1);
  CHUNK(11, pfA, pfB, 1);
  CHUNK(12, pfB, pfA, 0);

  float* srow = sums + (size_t)s_src[e]*64;
  #pragma unroll
  for (int q=0;q<4;q++) atomicAdd(srow + r*4 + q, o0[q]);
  #pragma unroll
  for (int m=0;m<3;m++) atomicAdd(srow + 32 + r*3 + m, o1[m]);
}

// ---- finalize: mean, node projection + residuals, write outputs
__global__ __launch_bounds__(256) void finalize_kernel(
    const float* __restrict__ sums, const float* __restrict__ cnt,
    const float* __restrict__ node, const float* __restrict__ l1,
    const float* __restrict__ pw, const float* __restrict__ pb,
    float* __restrict__ out)
{
  __shared__ float so[56];
  const int rnode = blockIdx.x;
  const int t = threadIdx.x;
  if (t < 56){
    const float c = cnt[rnode];
    so[t] = sums[rnode*64+t] / fmaxf(c, 1.0f);
  }
  __syncthreads();
  float acc = pb[t] + node[rnode*256+t];
  #pragma unroll
  for (int k=0;k<32;k++) acc += so[k]*pw[k*256+t];
  out[rnode*256+t] = acc;
  if (t < 24) out[NNODE*256 + rnode*24 + t] = so[32+t] + l1[rnode*24+t];
}

extern "C" void kernel_launch(void* const* d_in, const int* in_sizes, int n_in,
                              void* d_out, int out_size, void* d_ws, size_t ws_size,
                              hipStream_t stream)
{
  const float* node = (const float*)d_in[0];
  const float* pair = (const float*)d_in[1];
  const float* l1f  = (const float*)d_in[2];
  const float* esh  = (const float*)d_in[3];
  const float* plw  = (const float*)d_in[4];
  const float* plb  = (const float*)d_in[5];
  const float* pnw  = (const float*)d_in[6];
  const float* pnb  = (const float*)d_in[7];
  const float* lng  = (const float*)d_in[8];
  const float* lnb  = (const float*)d_in[9];
  const float* fc1w = (const float*)d_in[10];
  const float* fc1b = (const float*)d_in[11];
  const float* fc2w = (const float*)d_in[12];
  const float* fc2b = (const float*)d_in[13];
  const int* pidx = (const int*)d_in[14];
  const int* esrc = (const int*)d_in[15];
  const int* edst = (const int*)d_in[16];
  float* out = (float*)d_out;
  float* ws = (float*)d_ws;
  float* feats = ws;                         // 65536 f32
  float* sums  = ws + 65536;                 // 65536 f32
  float* cnt   = ws + 131072;                // 1024 f32
  ushort_t* fc1wT = (ushort_t*)(ws + 132096);   // 16384 bf16
  ushort_t* fc2wT = fc1wT + 16384;              // 212992 bf16

  hipMemsetAsync(sums, 0, (65536+1024)*sizeof(float), stream);
  prep_kernel<<<dim3(448), dim3(512), 0, stream>>>(fc1w, fc2w, fc1wT, fc2wT);
  feats_kernel<<<dim3(1024), dim3(64), 0, stream>>>(node, l1f, plw, plb, feats);
  count_kernel<<<dim3(256), dim3(256), 0, stream>>>(esrc, cnt);
  edge_kernel<<<dim3(1024), dim3(NT), 0, stream>>>(pair, pidx, esrc, edst, esh,
      lng, lnb, fc1wT, fc1b, fc2wT, fc2b, feats, sums);
  finalize_kernel<<<dim3(1024), dim3(256), 0, stream>>>(sums, cnt, node, l1f, pnw, pnb, out);
}

// Round 3
// 414.240 us; speedup vs baseline: 2.6739x; 1.0671x over previous
//
#include <hip/hip_runtime.h>

#define LQ 256
#define EDGES 65536
#define NNODE 1024
#define ET 64
#define NT 512

typedef __attribute__((ext_vector_type(8))) short bf16x8;
typedef __attribute__((ext_vector_type(4))) float f32x4;
typedef unsigned short ushort_t;
typedef unsigned int uint32;

constexpr float PW0c = 0.15811388300841897f;   // sqrt(1/40)
constexpr float PW1c = 0.25f;
constexpr float S3c  = 0.57735026918962576f;   // 1/sqrt(3)
constexpr float Kc   = 0.54772255750516611f;   // sqrt(3/10)

__device__ __forceinline__ ushort_t f2bf(float x){
  unsigned u = __float_as_uint(x);
  unsigned r = u + 0x7FFFu + ((u >> 16) & 1u);
  return (ushort_t)(r >> 16);
}

__device__ __forceinline__ float red8(float v){
  v += __shfl_xor(v, 1);
  v += __shfl_xor(v, 2);
  v += __shfl_xor(v, 4);
  return v;
}

// ---- fused setup: weight transpose/bf16 + feats + counts
__global__ __launch_bounds__(512) void setup_kernel(
    const float* __restrict__ fc1w, const float* __restrict__ fc2w,
    ushort_t* __restrict__ fc1wT, ushort_t* __restrict__ fc2wT,
    const float* __restrict__ node, const float* __restrict__ l1,
    const float* __restrict__ plw, const float* __restrict__ plb,
    float* __restrict__ feats,
    const int* __restrict__ esrc, float* __restrict__ cnt)
{
  const int b = blockIdx.x, t = threadIdx.x;
  if (b < 448){
    const int i = b*512 + t;
    if (i < 16384){
      const int j = i >> 7, k = i & 127;
      fc1wT[i] = f2bf(fc1w[k*128 + j]);
    } else {
      const int i2 = i - 16384;
      const int j = i2 >> 7, k = i2 & 127;
      fc2wT[i2] = f2bf(fc2w[(size_t)k*1664 + j]);
    }
  } else if (b < 576){
    const int rr = (b-448)*8 + (t >> 6);
    const int u = t & 63;
    if (u < 32){
      float acc = plb[u];
      const float* nr = node + rr*256;
      #pragma unroll 4
      for (int c=0;c<256;c++) acc += nr[c]*plw[c*32+u];
      feats[rr*64+u] = acc;
    } else if (u < 56){
      feats[rr*64+u] = l1[rr*24 + (u-32)];
    }
  } else {
    const int ee = (b-576)*512 + t;
    atomicAdd(&cnt[esrc[ee]], 1.0f);
  }
}

// ================= fused MFMA edge kernel =================
__global__ __launch_bounds__(NT, 4) void edge_kernel(
    const float* __restrict__ pair, const int* __restrict__ pidx,
    const int* __restrict__ esrc, const int* __restrict__ edst,
    const float* __restrict__ esh,
    const float* __restrict__ lng, const float* __restrict__ lnb,
    const ushort_t* __restrict__ fc1wT, const float* __restrict__ fc1b,
    const ushort_t* __restrict__ fc2wT, const float* __restrict__ fc2b,
    const float* __restrict__ feats, float* __restrict__ sums)
{
  __shared__ unsigned char R1[32768];  // coef f32[64][128] -> xn bf16[64][256B] -> wch f32[128][256B]
  __shared__ unsigned char R2[32768];  // B tiles bf16 [128][256B] swizzled
  __shared__ unsigned char R3[16384];  // h bf16 [64][256B] swizzled

  const int t = threadIdx.x;
  const int e0g = blockIdx.x * ET;
  const int e = t >> 3;   // 0..63 edge in tile
  const int r = t & 7;    // 0..7 sub-thread

  const uint4* gW1 = (const uint4*)fc1wT;
  const uint4* gW2 = (const uint4*)fc2wT;
  uint4 pf[4];
  #pragma unroll
  for (int u=0;u<4;u++) pf[u] = gW1[u*NT + t];   // fc1wT in flight

  // ---- phase 0: TP coefficient vectors -> R1 as f32 C[e][128]
  {
    const int dst = edst[e0g + e];
    const float* f = feats + (size_t)dst*64;
    const float* sh = esh + (size_t)(e0g+e)*9;
    const float sh0 = sh[0], s1x = sh[1], s1y = sh[2], s1z = sh[3];
    float* C = (float*)(R1 + e*512);
    #pragma unroll
    for (int q=0;q<4;q++){
      const int u = r*4+q;
      const float x0u = f[u];
      C[u]    = PW0c*sh0*x0u;          // c1[u]
      C[40+u] = PW1c*S3c*x0u;          // cx0[u]
    }
    {
      const int u = r;
      const float xx = f[32+u*3+0], xy = f[32+u*3+1], xz = f[32+u*3+2];
      C[32+u] = PW0c*S3c*(xx*s1x + xy*s1y + xz*s1z);   // c4[u]
      const float bc = PW1c*S3c*sh0;
      C[72+u*3+0] = bc*xx; C[72+u*3+1] = bc*xy; C[72+u*3+2] = bc*xz;  // b3[u][m]
      const float s20=sh[4], s21=sh[5], s22=sh[6], s23=sh[7], s24=sh[8];
      const float RXX = Kc*(-(1.f/3.f)*s22 - S3c*s24);
      const float RXY = Kc*S3c*s21;
      const float RXZ = Kc*S3c*s20;
      const float RYY = Kc*((2.f/3.f)*s22);
      const float RYZ = Kc*S3c*s23;
      const float RZZ = Kc*(-(1.f/3.f)*s22 + S3c*s24);
      C[96+u*3+0] = PW1c*(xx*RXX + xy*RXY + xz*RXZ);   // t5p[u][m]
      C[96+u*3+1] = PW1c*(xx*RXY + xy*RYY + xz*RYZ);
      C[96+u*3+2] = PW1c*(xx*RXZ + xy*RYZ + xz*RZZ);
      if (r==0){ C[120]=s1x; C[121]=s1y; C[122]=s1z; }
    }
  }
  __syncthreads();   // B0: coefficients visible

  // coefficient registers: cr[s] = C[e][r*16+s]
  float cr[16];
  {
    const unsigned char* cp = R1 + e*512 + r*64;
    *(float4*)&cr[0]  = *(const float4*)(cp);
    *(float4*)&cr[4]  = *(const float4*)(cp+16);
    *(float4*)&cr[8]  = *(const float4*)(cp+32);
    *(float4*)&cr[12] = *(const float4*)(cp+48);
  }
  __syncthreads();   // B1: coef reads done, R1 reusable

#define CF(I) __shfl(cr[(I)&15], (t & 56) + ((I)>>4))

  // ---- phase 1: gather pair row + LayerNorm -> xn (bf16, swizzled) in R1
  {
    const int ee = e0g + e;
    const int pb = pidx[ee], pi_ = pidx[EDGES+ee], pj = pidx[2*EDGES+ee];
    const float4* prow = (const float4*)(pair + (((size_t)pb*LQ + pi_)*LQ + pj)*128);
    float4 v[4];
    #pragma unroll
    for (int k=0;k<4;k++) v[k] = prow[r*4+k];
    float s=0.f, s2=0.f;
    #pragma unroll
    for (int k=0;k<4;k++){
      s  += v[k].x+v[k].y+v[k].z+v[k].w;
      s2 += v[k].x*v[k].x + v[k].y*v[k].y + v[k].z*v[k].z + v[k].w*v[k].w;
    }
    s = red8(s); s2 = red8(s2);
    const float mean = s * (1.f/128.f);
    const float var  = s2 * (1.f/128.f) - mean*mean;
    const float rstd = rsqrtf(var + 1e-5f);
    uint32 pk[8];
    #pragma unroll
    for (int k=0;k<4;k++){
      const int c = r*16 + k*4;
      const float4 g  = *(const float4*)(lng + c);
      const float4 bb = *(const float4*)(lnb + c);
      float4 o;
      o.x = (v[k].x-mean)*rstd*g.x + bb.x;
      o.y = (v[k].y-mean)*rstd*g.y + bb.y;
      o.z = (v[k].z-mean)*rstd*g.z + bb.z;
      o.w = (v[k].w-mean)*rstd*g.w + bb.w;
      pk[k*2]   = (uint32)f2bf(o.x) | ((uint32)f2bf(o.y)<<16);
      pk[k*2+1] = (uint32)f2bf(o.z) | ((uint32)f2bf(o.w)<<16);
    }
    const int xr = (e&7)<<4;
    *(uint4*)(R1 + e*256 + ((r*32) ^ xr))    = make_uint4(pk[0],pk[1],pk[2],pk[3]);
    *(uint4*)(R1 + e*256 + ((r*32+16) ^ xr)) = make_uint4(pk[4],pk[5],pk[6],pk[7]);
  }

  // stage fc1wT -> R2 (swizzled); issue chunk-0 loads
  #pragma unroll
  for (int u=0;u<4;u++){
    const int v = u*NT + t; const int n = v>>4; const int c = v&15;
    *(uint4*)(R2 + n*256 + ((c*16) ^ ((n&7)<<4))) = pf[u];
  }
  #pragma unroll
  for (int u=0;u<4;u++) pf[u] = gW2[u*NT + t];
  __syncthreads();   // B2: xn + fc1wT visible

  // ---- wave/lane decode for MFMA
  const int l = t & 63;
  const int l15 = l & 15;
  const int lh = l >> 4;                 // 0..3
  const int wv = t >> 6;                 // wave 0..7
  const int mt0 = (wv & 1) * 2;          // edge-tile pair
  const int npr = wv >> 1;               // j-tile pair 0..3
  const int erow0 = mt0*16 + l15;
  const int ax = (l15 & 7) << 4;         // XOR swizzle (row&7==l15&7 for all our rows)
  const int jc0 = npr*32 + l15;
  const int ebase = mt0*16 + lh*4;
  const int e4 = e*4;

  // ---- fc1: h = relu(xn @ fc1w + b) -> R3
  {
    const float bj0 = fc1b[jc0], bj1 = fc1b[jc0+16];
    f32x4 acc00 = {bj0,bj0,bj0,bj0}, acc01 = {bj1,bj1,bj1,bj1};
    f32x4 acc10 = acc00, acc11 = acc01;
    #pragma unroll
    for (int kk=0;kk<4;kk++){
      const int ko = kk*64 + lh*16;
      bf16x8 a0 = *(const bf16x8*)(R1 + erow0*256 + (ko ^ ax));
      bf16x8 a1 = *(const bf16x8*)(R1 + (erow0+16)*256 + (ko ^ ax));
      bf16x8 b0 = *(const bf16x8*)(R2 + jc0*256 + (ko ^ ax));
      bf16x8 b1 = *(const bf16x8*)(R2 + (jc0+16)*256 + (ko ^ ax));
      acc00 = __builtin_amdgcn_mfma_f32_16x16x32_bf16(a0,b0,acc00,0,0,0);
      acc01 = __builtin_amdgcn_mfma_f32_16x16x32_bf16(a0,b1,acc01,0,0,0);
      acc10 = __builtin_amdgcn_mfma_f32_16x16x32_bf16(a1,b0,acc10,0,0,0);
      acc11 = __builtin_amdgcn_mfma_f32_16x16x32_bf16(a1,b1,acc11,0,0,0);
    }
    #pragma unroll
    for (int q=0;q<4;q++){
      const int ea = ebase + q, eb = ea + 16;
      *(ushort_t*)(R3 + ea*256 + ((jc0*2) ^ ((ea&7)<<4)))      = f2bf(fmaxf(acc00[q],0.f));
      *(ushort_t*)(R3 + ea*256 + (((jc0+16)*2) ^ ((ea&7)<<4))) = f2bf(fmaxf(acc01[q],0.f));
      *(ushort_t*)(R3 + eb*256 + ((jc0*2) ^ ((eb&7)<<4)))      = f2bf(fmaxf(acc10[q],0.f));
      *(ushort_t*)(R3 + eb*256 + (((jc0+16)*2) ^ ((eb&7)<<4))) = f2bf(fmaxf(acc11[q],0.f));
    }
  }
  __syncthreads();   // B3: h visible, R2 free

  // stage chunk 0, issue chunk-1 loads
  #pragma unroll
  for (int u=0;u<4;u++){
    const int v = u*NT + t; const int n = v>>4; const int c = v&15;
    *(uint4*)(R2 + n*256 + ((c*16) ^ ((n&7)<<4))) = pf[u];
  }
  #pragma unroll
  for (int u=0;u<4;u++) pf[u] = gW2[2048 + u*NT + t];

  float o0[4] = {0.f,0.f,0.f,0.f};
  float o1[3] = {0.f,0.f,0.f};

  // w-value read from R1 (f32 [row j][64 e], XOR-swizzled 16B groups)
#define WVX(ROW) (*(const float*)(R1 + (ROW)*256 + (e4 ^ (((ROW)&7)<<4))))

#define APPLY(CB) do {                                                        \
    if ((CB) < 8){                                                            \
      const int u0 = (CB)*4;                                                  \
      const float k0=CF(u0), k1=CF(u0+1), k2=CF(u0+2), k3=CF(u0+3);           \
      _Pragma("unroll")                                                       \
      for (int q=0;q<4;q++){                                                  \
        const int wi = r*4+q;                                                 \
        o0[q] += k0*WVX(wi) + k1*WVX(32+wi) + k2*WVX(64+wi) + k3*WVX(96+wi);  \
      }                                                                       \
    } else if ((CB) < 10){                                                    \
      const int u0 = ((CB)-8)*16;                                             \
      float S = 0.f;                                                          \
      _Pragma("unroll")                                                       \
      for (int du=0;du<16;du++)                                               \
        S += CF(40+u0+du)*WVX(du*8+r);                                        \
      o1[0] += S*CF(120); o1[1] += S*CF(121); o1[2] += S*CF(122);             \
    } else if ((CB) == 10){                                                   \
      _Pragma("unroll")                                                       \
      for (int u=0;u<8;u++){                                                  \
        const float wvv = WVX(u*8+r);                                         \
        o1[0] += CF(72+u*3+0)*wvv;                                            \
        o1[1] += CF(72+u*3+1)*wvv;                                            \
        o1[2] += CF(72+u*3+2)*wvv;                                            \
      }                                                                       \
      _Pragma("unroll")                                                       \
      for (int q=0;q<4;q++){                                                  \
        const int wi = r*4+q;                                                 \
        o0[q] += CF(32)*WVX(64+wi) + CF(33)*WVX(96+wi);                       \
      }                                                                       \
    } else if ((CB) == 11){                                                   \
      const float k0=CF(34), k1=CF(35), k2=CF(36), k3=CF(37);                 \
      _Pragma("unroll")                                                       \
      for (int q=0;q<4;q++){                                                  \
        const int wi = r*4+q;                                                 \
        o0[q] += k0*WVX(wi) + k1*WVX(32+wi) + k2*WVX(64+wi) + k3*WVX(96+wi);  \
      }                                                                       \
    } else {                                                                  \
      const float k0=CF(38), k1=CF(39);                                       \
      _Pragma("unroll")                                                       \
      for (int q=0;q<4;q++){                                                  \
        const int wi = r*4+q;                                                 \
        o0[q] += k0*WVX(wi) + k1*WVX(32+wi);                                  \
      }                                                                       \
      _Pragma("unroll")                                                       \
      for (int u=0;u<8;u++){                                                  \
        const float wvv = WVX(64+u*8+r);                                      \
        o1[0] += CF(96+u*3+0)*wvv;                                            \
        o1[1] += CF(96+u*3+1)*wvv;                                            \
        o1[2] += CF(96+u*3+2)*wvv;                                            \
      }                                                                       \
    }                                                                         \
  } while(0)

#define CHUNKM(CB, DO_STAGE, DO_LOAD) do {                                    \
    __syncthreads();   /* bar A: B-tile visible, prev apply done with R1 */   \
    {                                                                         \
      const float bj0 = fc2b[(CB)*128 + jc0];                                 \
      const float bj1 = fc2b[(CB)*128 + jc0 + 16];                            \
      f32x4 acc00 = {bj0,bj0,bj0,bj0}, acc01 = {bj1,bj1,bj1,bj1};             \
      f32x4 acc10 = acc00, acc11 = acc01;                                     \
      _Pragma("unroll")                                                       \
      for (int kk=0;kk<4;kk++){                                               \
        const int ko = kk*64 + lh*16;                                         \
        bf16x8 a0 = *(const bf16x8*)(R3 + erow0*256 + (ko ^ ax));             \
        bf16x8 a1 = *(const bf16x8*)(R3 + (erow0+16)*256 + (ko ^ ax));        \
        bf16x8 b0 = *(const bf16x8*)(R2 + jc0*256 + (ko ^ ax));               \
        bf16x8 b1 = *(const bf16x8*)(R2 + (jc0+16)*256 + (ko ^ ax));          \
        acc00 = __builtin_amdgcn_mfma_f32_16x16x32_bf16(a0,b0,acc00,0,0,0);   \
        acc01 = __builtin_amdgcn_mfma_f32_16x16x32_bf16(a0,b1,acc01,0,0,0);   \
        acc10 = __builtin_amdgcn_mfma_f32_16x16x32_bf16(a1,b0,acc10,0,0,0);   \
        acc11 = __builtin_amdgcn_mfma_f32_16x16x32_bf16(a1,b1,acc11,0,0,0);   \
      }                                                                       \
      *(f32x4*)(R1 + jc0*256      + ((ebase*4) ^ ax))      = acc00;           \
      *(f32x4*)(R1 + (jc0+16)*256 + ((ebase*4) ^ ax))      = acc01;           \
      *(f32x4*)(R1 + jc0*256      + (((ebase+16)*4) ^ ax)) = acc10;           \
      *(f32x4*)(R1 + (jc0+16)*256 + (((ebase+16)*4) ^ ax)) = acc11;           \
    }                                                                         \
    __syncthreads();   /* bar B: w-chunk visible, R2 reads done */            \
    APPLY(CB);                                                                \
    if (DO_STAGE){                                                            \
      _Pragma("unroll")                                                       \
      for (int u=0;u<4;u++){                                                  \
        const int v = u*NT + t; const int n = v>>4; const int c = v&15;       \
        *(uint4*)(R2 + n*256 + ((c*16) ^ ((n&7)<<4))) = pf[u];                \
      }                                                                       \
      if (DO_LOAD){                                                           \
        _Pragma("unroll")                                                     \
        for (int u=0;u<4;u++) pf[u] = gW2[((CB)+2)*2048 + u*NT + t];          \
      }                                                                       \
    }                                                                         \
  } while(0)

  CHUNKM(0,1,1);  CHUNKM(1,1,1);  CHUNKM(2,1,1);  CHUNKM(3,1,1);
  CHUNKM(4,1,1);  CHUNKM(5,1,1);  CHUNKM(6,1,1);  CHUNKM(7,1,1);
  CHUNKM(8,1,1);  CHUNKM(9,1,1);  CHUNKM(10,1,1); CHUNKM(11,1,0);
  CHUNKM(12,0,0);

  const int src = esrc[e0g + e];
  float* srow = sums + (size_t)src*64;
  #pragma unroll
  for (int q=0;q<4;q++) atomicAdd(srow + r*4 + q, o0[q]);
  #pragma unroll
  for (int m=0;m<3;m++) atomicAdd(srow + 32 + r*3 + m, o1[m]);
}

// ---- finalize: mean, node projection + residuals, write outputs
__global__ __launch_bounds__(256) void finalize_kernel(
    const float* __restrict__ sums, const float* __restrict__ cnt,
    const float* __restrict__ node, const float* __restrict__ l1,
    const float* __restrict__ pw, const float* __restrict__ pb,
    float* __restrict__ out)
{
  __shared__ float so[56];
  const int rnode = blockIdx.x;
  const int t = threadIdx.x;
  if (t < 56){
    const float c = cnt[rnode];
    so[t] = sums[rnode*64+t] / fmaxf(c, 1.0f);
  }
  __syncthreads();
  float acc = pb[t] + node[rnode*256+t];
  #pragma unroll
  for (int k=0;k<32;k++) acc += so[k]*pw[k*256+t];
  out[rnode*256+t] = acc;
  if (t < 24) out[NNODE*256 + rnode*24 + t] = so[32+t] + l1[rnode*24+t];
}

extern "C" void kernel_launch(void* const* d_in, const int* in_sizes, int n_in,
                              void* d_out, int out_size, void* d_ws, size_t ws_size,
                              hipStream_t stream)
{
  const float* node = (const float*)d_in[0];
  const float* pair = (const float*)d_in[1];
  const float* l1f  = (const float*)d_in[2];
  const float* esh  = (const float*)d_in[3];
  const float* plw  = (const float*)d_in[4];
  const float* plb  = (const float*)d_in[5];
  const float* pnw  = (const float*)d_in[6];
  const float* pnb  = (const float*)d_in[7];
  const float* lng  = (const float*)d_in[8];
  const float* lnb  = (const float*)d_in[9];
  const float* fc1w = (const float*)d_in[10];
  const float* fc1b = (const float*)d_in[11];
  const float* fc2w = (const float*)d_in[12];
  const float* fc2b = (const float*)d_in[13];
  const int* pidx = (const int*)d_in[14];
  const int* esrc = (const int*)d_in[15];
  const int* edst = (const int*)d_in[16];
  float* out = (float*)d_out;
  float* ws = (float*)d_ws;
  float* feats = ws;                            // 65536 f32
  float* sums  = ws + 65536;                    // 65536 f32
  float* cnt   = ws + 131072;                   // 1024 f32
  ushort_t* fc1wT = (ushort_t*)(ws + 132096);   // 16384 bf16
  ushort_t* fc2wT = fc1wT + 16384;              // 212992 bf16

  hipMemsetAsync(sums, 0, (65536+1024)*sizeof(float), stream);
  setup_kernel<<<dim3(704), dim3(512), 0, stream>>>(fc1w, fc2w, fc1wT, fc2wT,
      node, l1f, plw, plb, feats, esrc, cnt);
  edge_kernel<<<dim3(1024), dim3(NT), 0, stream>>>(pair, pidx, esrc, edst, esh,
      lng, lnb, fc1wT, fc1b, fc2wT, fc2b, feats, sums);
  finalize_kernel<<<dim3(1024), dim3(256), 0, stream>>>(sums, cnt, node, l1f, pnw, pnb, out);
}